// Round 20
// baseline (155.397 us; speedup 1.0000x reference)
//
#include <hip/hip_runtime.h>
#include <hip/hip_bf16.h>
#include <math.h>

// DscaGRUCell rev 18 — rev 15 (131.9us best) + ONE change: AFP32 phase-A path
// becomes A-to-REGISTER (per-lane private fragments, plain vector loads,
// 2-deep named-set prefetch) + B-via-gload_lds (4-buf). Halves gload_lds
// traffic per step; A rides the vector-load path. All else byte-identical.

#define TAU_F 0.5f

typedef __bf16 bf16x8 __attribute__((ext_vector_type(8)));
typedef __bf16 bf16x4 __attribute__((ext_vector_type(4)));
typedef float f32x4 __attribute__((ext_vector_type(4)));

__device__ __forceinline__ void gload16(const void* g, void* l) {
    __builtin_amdgcn_global_load_lds(
        (const __attribute__((address_space(1))) void*)g,
        (__attribute__((address_space(3))) void*)l, 16, 0, 0);
}

struct SubGemm {
    const void* A;    // M x lda (f32 if AFP32 else bf16)
    int lda;
    int Kvalid;       // AFP32: valid A cols (addr clamp; BT zero-padded beyond)
    const __bf16* BT; // N x Kpad row-major (pre-transposed, zero-padded bf16)
    int ldbt;
    float* C;         // out base (fp32, or bf16 when obf16)
    int ldc;
    long long strideC;
    int Ksub;         // K per split slice (mult of 64 for AFP32, 32 else)
    int nbx;          // col tiles (N/128)
    int pairSplit;    // ct >= this uses A + pairAOff
    int pairAOff;
    int obf16;        // store bf16 instead of f32
};

template <bool AFP32>
__global__ __launch_bounds__(256) void gemm_dual(SubGemm g1, SubGemm g2, int blocks1)
{
    __shared__ __attribute__((aligned(16))) char lds[AFP32 ? 32768 : 49152];

    const int tid = threadIdx.x, w = tid >> 6, l = tid & 63;

    // T1 XCD-chunked swizzle (nwg % 8 == 0 for all launches here)
    const int gx = gridDim.x;
    const int nwg = gx * (int)gridDim.y;
    const int hw = (int)blockIdx.y * gx + (int)blockIdx.x;
    const int lg = (hw & 7) * (nwg >> 3) + (hw >> 3);
    const int bxl_lin = lg % gx;
    const int by = lg / gx;

    const bool second = bxl_lin >= blocks1;
    const SubGemm& g = second ? g2 : g1;
    const int bxl = second ? bxl_lin - blocks1 : bxl_lin;
    const int ct = bxl % g.nbx, spl = bxl / g.nbx;
    const int brow = by * 64, bcol = ct * 128;
    const int k_begin = spl * g.Ksub;
    const int nt = g.Ksub >> 5;
    const int aoff = (ct >= g.pairSplit) ? g.pairAOff : 0;

    const int sbr = w * 32 + (l >> 2);        // B staging rows (2 issues)
    const int seg = (l & 3) * 8;

    const __bf16* Bg0 = g.BT + (size_t)(bcol + sbr) * g.ldbt + seg + k_begin;
    const __bf16* Bg1 = Bg0 + (size_t)16 * g.ldbt;

    f32x4 acc[2][4] = {};
    const int fr = l & 15, fk = (l >> 4) * 8;
    const int wr = (w >> 1) * 32, wc = (w & 1) * 64;
    const int kmax = (nt - 1) * 32;

    if constexpr (AFP32) {
        // Hybrid: A direct-to-register (per-lane private, plain vector loads,
        // 2x wave-pair redundancy -> L1/L2), B via gload_lds 4-buf.
        // Per slot (issue order fixed): [A-reg x4][B gload_lds x2] = 6 vmem.
        // Depth 2 -> queue 12; vmcnt(6) at step top completes slot t exactly.
        auto Bs = (__bf16 (*)[128][32])lds;    // 4 x 8KB

        const float* Ar0 = (const float*)g.A + aoff + (size_t)(brow + wr + fr) * g.lda;
        const float* Ar1 = Ar0 + (size_t)16 * g.lda;
        const int kcl = g.Kvalid - 8;   // clamp keeps 8-f32 read in-bounds;
                                        // B^T zero-pad kills clamped products

#define ALOAD(d0, d1, d2, d3, slot)                                           \
        {                                                                     \
            const int _k = ((slot) * 32 < kmax) ? (slot) * 32 : kmax;         \
            int c = k_begin + _k + fk;                                        \
            c = c < kcl ? c : kcl;                                            \
            d0 = *(const f32x4*)(Ar0 + c);                                    \
            d1 = *(const f32x4*)(Ar0 + c + 4);                                \
            d2 = *(const f32x4*)(Ar1 + c);                                    \
            d3 = *(const f32x4*)(Ar1 + c + 4);                                \
        }
#define BLOAD(slot)                                                           \
        {                                                                     \
            const int _s = (slot);                                            \
            const int _k = (_s * 32 < kmax) ? _s * 32 : kmax;                 \
            const int _b = _s & 3;                                            \
            gload16(Bg0 + _k, &Bs[_b][w * 32][0]);                            \
            gload16(Bg1 + _k, &Bs[_b][w * 32 + 16][0]);                       \
        }
#define ASTEP(t_, s0, s1, s2, s3)                                             \
        {                                                                     \
            asm volatile("s_waitcnt vmcnt(6)" ::: "memory");                  \
            asm volatile("s_waitcnt lgkmcnt(0)" ::: "memory");                \
            __builtin_amdgcn_s_barrier();                                     \
            const int _bi = (t_) & 3;                                         \
            bf16x8 a[2], b[4];                                                \
            _Pragma("unroll")                                                 \
            for (int z = 0; z < 4; ++z) {                                     \
                a[0][z] = (__bf16)s0[z]; a[0][4 + z] = (__bf16)s1[z];         \
                a[1][z] = (__bf16)s2[z]; a[1][4 + z] = (__bf16)s3[z];         \
            }                                                                 \
            _Pragma("unroll")                                                 \
            for (int n = 0; n < 4; ++n)                                       \
                b[n] = *(const bf16x8*)&Bs[_bi][wc + n * 16 + fr][fk];        \
            ALOAD(s0, s1, s2, s3, (t_) + 2)                                   \
            BLOAD((t_) + 2)                                                   \
            _Pragma("unroll")                                                 \
            for (int m = 0; m < 2; ++m)                                       \
                _Pragma("unroll")                                             \
                for (int n = 0; n < 4; ++n)                                   \
                    acc[m][n] = __builtin_amdgcn_mfma_f32_16x16x32_bf16(      \
                        a[m], b[n], acc[m][n], 0, 0, 0);                      \
        }

        f32x4 p0, p1, p2, p3, q0, q1, q2, q3;
        ALOAD(p0, p1, p2, p3, 0) BLOAD(0)
        ALOAD(q0, q1, q2, q3, 1) BLOAD(1)

        for (int t = 0; t < nt; t += 2) {     // nt even (32 or 16)
            ASTEP(t,     p0, p1, p2, p3)
            ASTEP(t + 1, q0, q1, q2, q3)
        }
#undef ASTEP
#undef BLOAD
#undef ALOAD
    } else {
        // LDS: As 4 x [64][32] bf16 (16KB) | Bs 4 x [128][32] bf16 (32KB)
        auto As = (__bf16 (*)[64][32])lds;
        auto Bs = (__bf16 (*)[128][32])(lds + 16384);

        const int sar = w * 16 + (l >> 2);
        const __bf16* Ar = (const __bf16*)g.A + aoff
                         + (size_t)(brow + sar) * g.lda + seg + k_begin;

#define ISSUE_AB(slot)                                                        \
        {                                                                     \
            const int _s = (slot);                                            \
            const int _k = (_s * 32 < kmax) ? _s * 32 : kmax;                 \
            const int _b = _s & 3;                                            \
            gload16(Ar + _k,  &As[_b][w * 16][0]);                            \
            gload16(Bg0 + _k, &Bs[_b][w * 32][0]);                            \
            gload16(Bg1 + _k, &Bs[_b][w * 32 + 16][0]);                       \
        }

        ISSUE_AB(0) ISSUE_AB(1) ISSUE_AB(2)

        for (int t = 0; t < nt; ++t) {
            asm volatile("s_waitcnt vmcnt(6)" ::: "memory");
            asm volatile("s_waitcnt lgkmcnt(0)" ::: "memory");
            __builtin_amdgcn_s_barrier();

            const int bi = t & 3;
            bf16x8 a[2], b[4];
#pragma unroll
            for (int m = 0; m < 2; ++m) a[m] = *(const bf16x8*)&As[bi][wr + m * 16 + fr][fk];
#pragma unroll
            for (int n = 0; n < 4; ++n) b[n] = *(const bf16x8*)&Bs[bi][wc + n * 16 + fr][fk];

            ISSUE_AB(t + 3)

#pragma unroll
            for (int m = 0; m < 2; ++m)
#pragma unroll
                for (int n = 0; n < 4; ++n)
                    acc[m][n] = __builtin_amdgcn_mfma_f32_16x16x32_bf16(a[m], b[n], acc[m][n], 0, 0, 0);
        }
#undef ISSUE_AB
    }

    // epilogue. C/D: col=lane&15, row=(lane>>4)*4+reg
    const int fq = (l >> 4) * 4;
    if (g.obf16) {
        __bf16* Cb = (__bf16*)g.C + (size_t)spl * g.strideC;
#pragma unroll
        for (int m = 0; m < 2; ++m)
#pragma unroll
            for (int n = 0; n < 4; ++n)
#pragma unroll
                for (int r = 0; r < 4; ++r) {
                    int row = brow + wr + m * 16 + fq + r;
                    int col = bcol + wc + n * 16 + fr;
                    Cb[(size_t)row * g.ldc + col] = (__bf16)acc[m][n][r];
                }
    } else {
        float* C = g.C + (size_t)spl * g.strideC;
#pragma unroll
        for (int m = 0; m < 2; ++m)
#pragma unroll
            for (int n = 0; n < 4; ++n)
#pragma unroll
                for (int r = 0; r < 4; ++r) {
                    int row = brow + wr + m * 16 + fq + r;
                    int col = bcol + wc + n * 16 + fr;
                    C[(size_t)row * g.ldc + col] = acc[m][n][r];
                }
    }
}

// ---------------- G8 + fused GRU final: h = z*hprev + (1-z)*tanh(xh+acc) ----
__global__ __launch_bounds__(256) void gemm_g8(
    const __bf16* __restrict__ A, const __bf16* __restrict__ BT,
    const float* __restrict__ mx, const float* __restrict__ mi2,
    const float* __restrict__ hprev, const float* __restrict__ bias,
    float* __restrict__ h)
{
    __shared__ __attribute__((aligned(16))) char lds[49152];

    const int tid = threadIdx.x, w = tid >> 6, l = tid & 63;

    const int gx = gridDim.x;
    const int nwg = gx * (int)gridDim.y;
    const int hw = (int)blockIdx.y * gx + (int)blockIdx.x;
    const int lg = (hw & 7) * (nwg >> 3) + (hw >> 3);
    const int ct = lg % gx;
    const int by = lg / gx;

    const int brow = by * 64, bcol = ct * 128;
    const int nt = 16;                         // K = 512

    const int sbr = w * 32 + (l >> 2);
    const int seg = (l & 3) * 8;

    const __bf16* Bg0 = BT + (size_t)(bcol + sbr) * 512 + seg;
    const __bf16* Bg1 = Bg0 + (size_t)16 * 512;

    f32x4 acc[2][4] = {};
    const int fr = l & 15, fk = (l >> 4) * 8;
    const int wr = (w >> 1) * 32, wc = (w & 1) * 64;
    const int kmax = (nt - 1) * 32;

    auto As = (__bf16 (*)[64][32])lds;
    auto Bs = (__bf16 (*)[128][32])(lds + 16384);

    const int sar = w * 16 + (l >> 2);
    const __bf16* Ar = A + (size_t)(brow + sar) * 512 + seg;

#define ISSUE_G8(slot)                                                        \
    {                                                                         \
        const int _s = (slot);                                                \
        const int _k = (_s * 32 < kmax) ? _s * 32 : kmax;                     \
        const int _b = _s & 3;                                                \
        gload16(Ar + _k,  &As[_b][w * 16][0]);                                \
        gload16(Bg0 + _k, &Bs[_b][w * 32][0]);                                \
        gload16(Bg1 + _k, &Bs[_b][w * 32 + 16][0]);                           \
    }

    ISSUE_G8(0) ISSUE_G8(1) ISSUE_G8(2)

    for (int t = 0; t < nt; ++t) {
        asm volatile("s_waitcnt vmcnt(6)" ::: "memory");
        asm volatile("s_waitcnt lgkmcnt(0)" ::: "memory");
        __builtin_amdgcn_s_barrier();

        const int bi = t & 3;
        bf16x8 a[2], b[4];
#pragma unroll
        for (int m = 0; m < 2; ++m) a[m] = *(const bf16x8*)&As[bi][wr + m * 16 + fr][fk];
#pragma unroll
        for (int n = 0; n < 4; ++n) b[n] = *(const bf16x8*)&Bs[bi][wc + n * 16 + fr][fk];

        ISSUE_G8(t + 3)

#pragma unroll
        for (int m = 0; m < 2; ++m)
#pragma unroll
            for (int n = 0; n < 4; ++n)
                acc[m][n] = __builtin_amdgcn_mfma_f32_16x16x32_bf16(a[m], b[n], acc[m][n], 0, 0, 0);
    }
#undef ISSUE_G8

    // fused GRU final epilogue
    const int fq = (l >> 4) * 4;
#pragma unroll
    for (int m = 0; m < 2; ++m)
#pragma unroll
        for (int n = 0; n < 4; ++n)
#pragma unroll
            for (int r = 0; r < 4; ++r) {
                int row = brow + wr + m * 16 + fq + r;
                int col = bcol + wc + n * 16 + fr;
                float xz = mx[(size_t)row * 1536 + col]        + bias[col];
                float xh = mx[(size_t)row * 1536 + 1024 + col] + bias[1024 + col];
                float mz = mi2[(size_t)row * 1024 + col];
                float hp = hprev[(size_t)row * 512 + col];
                float z  = 1.f / (1.f + expf(-(xz + mz)));
                float hh = tanhf(xh + acc[m][n][r]);
                h[(size_t)row * 512 + col] = z * hp + (1.f - z) * hh;
            }
}

// ---------------- prep: LDS-tiled weight transposes --------------------------
__global__ __launch_bounds__(256) void prep_wT(
    const float* __restrict__ ew1, const float* __restrict__ ew2,
    const float* __restrict__ w12, const float* __restrict__ u12,
    const float* __restrict__ v12, const float* __restrict__ w21,
    const float* __restrict__ u21, const float* __restrict__ v21,
    const float* __restrict__ cd_w, const float* __restrict__ cw_w,
    const float* __restrict__ kern, const float* __restrict__ rkern,
    __bf16* __restrict__ WT, __bf16* __restrict__ WcatT,
    __bf16* __restrict__ cdT, __bf16* __restrict__ cwT,
    __bf16* __restrict__ kernT, __bf16* __restrict__ rkernT)
{
    __shared__ float tile[64][65];
    const int b = blockIdx.x, tid = threadIdx.x;
    const int tr = tid >> 6, tc = tid & 63;

    const float* src = nullptr;
    int ldsrc = 0, srow0 = 0, scol0 = 0, kvalid = 1 << 30;
    __bf16* dst; int ldd, n0, k0;
    bool zero = false;

    if (b < 256) {                         // WT: out 512 x 2048
        int q = b; n0 = (q >> 5) * 64; k0 = (q & 31) * 64;
        dst = WT; ldd = 2048; kvalid = 2000; ldsrc = 256; srow0 = k0;
        if (n0 < 256) { src = ew1; scol0 = n0; } else { src = ew2; scol0 = n0 - 256; }
    } else if (b < 384) {                  // WcatT: out 1024 x 512
        int q = b - 256; n0 = (q >> 3) * 64; k0 = (q & 7) * 64;
        dst = WcatT; ldd = 512; ldsrc = 256; srow0 = k0 & 255; scol0 = n0 & 255;
        int qn = n0 >> 8; bool khi = k0 >= 256;
        if (qn == 0)      src = khi ? u12 : w12;
        else if (qn == 1) src = khi ? w21 : u21;
        else if (qn == 2) { if (khi) src = v12; else zero = true; }
        else              { if (khi) zero = true; else src = v21; }
    } else if (b < 448) {                  // cdT
        int q = b - 384; n0 = (q >> 3) * 64; k0 = (q & 7) * 64;
        src = cd_w; ldsrc = 512; srow0 = k0; scol0 = n0; dst = cdT; ldd = 512;
    } else if (b < 512) {                  // cwT
        int q = b - 448; n0 = (q >> 3) * 64; k0 = (q & 7) * 64;
        src = cw_w; ldsrc = 512; srow0 = k0; scol0 = n0; dst = cwT; ldd = 512;
    } else if (b < 704) {                  // kernT
        int q = b - 512; n0 = (q >> 3) * 64; k0 = (q & 7) * 64;
        src = kern; ldsrc = 1536; srow0 = k0; scol0 = n0; dst = kernT; ldd = 512;
    } else {                               // rkernT
        int q = b - 704; n0 = (q >> 3) * 64; k0 = (q & 7) * 64;
        src = rkern; ldsrc = 1536; srow0 = k0; scol0 = n0; dst = rkernT; ldd = 512;
    }

#pragma unroll
    for (int p = 0; p < 16; ++p) {
        int kr = p * 4 + tr;
        float v = 0.f;
        if (!zero && (srow0 + kr) < kvalid)
            v = src[(size_t)(srow0 + kr) * ldsrc + scol0 + tc];
        tile[kr][tc] = v;
    }
    __syncthreads();
#pragma unroll
    for (int p = 0; p < 16; ++p) {
        int nr = p * 4 + tr;
        dst[(size_t)(n0 + nr) * ldd + k0 + tc] = (__bf16)tile[tc][nr];
    }
}

// ---------------- R-A: E = bf16(sum2 P12), cro = bf16(tanh(P4 + cd_b)) ------
__global__ __launch_bounds__(256) void reduce_A(
    const float* __restrict__ P12, const float* __restrict__ P4,
    const float* __restrict__ cd_b,
    __bf16* __restrict__ E, __bf16* __restrict__ cro)
{
    const int S = 1 << 21;
    int b = blockIdx.x;
    int i = (((b & 2047) * 256) + threadIdx.x) * 4;
    if (b < 2048) {
        f32x4 p0 = *(const f32x4*)(P12 + i);
        f32x4 p1 = *(const f32x4*)(P12 + S + i);
        __bf16 o[4];
#pragma unroll
        for (int j = 0; j < 4; ++j) o[j] = (__bf16)(p0[j] + p1[j]);
        *(bf16x4*)&E[i] = *(bf16x4*)o;
    } else {
        f32x4 p0 = *(const f32x4*)(P4 + i);
        int c = i & 511;
        __bf16 o[4];
#pragma unroll
        for (int j = 0; j < 4; ++j) o[j] = (__bf16)tanhf(p0[j] + cd_b[c + j]);
        *(bf16x4*)&cro[i] = *(bf16x4*)o;
    }
}

// ---------------- fuse1: attention + x + crohis_new, and hprev ---------------
__global__ __launch_bounds__(256) void fuse1(
    const __bf16* __restrict__ T, const __bf16* __restrict__ E,
    const float* __restrict__ crohis,
    const float* __restrict__ P5,
    const float* __restrict__ h_tm1, const float* __restrict__ cw_b,
    __bf16* __restrict__ x, float* __restrict__ cro_out,
    float* __restrict__ hprev, __bf16* __restrict__ hprev_bf)
{
    __shared__ float s4[4];
    int b = blockIdx.x;
    int j = threadIdx.x;
    if (b < 4096) {
        const __bf16* t = T + (size_t)b * 1024;
        float s12 = tanhf((float)t[j])       * (float)t[512 + j];
        float s21 = tanhf((float)t[256 + j]) * (float)t[768 + j];
        float v = s12;
#pragma unroll
        for (int o = 32; o >= 1; o >>= 1) v = fmaxf(v, __shfl_xor(v, o, 64));
        __syncthreads(); if ((j & 63) == 0) s4[j >> 6] = v; __syncthreads();
        float m12 = fmaxf(fmaxf(s4[0], s4[1]), fmaxf(s4[2], s4[3]));
        float e12 = expf(s12 - m12);
        v = e12;
#pragma unroll
        for (int o = 32; o >= 1; o >>= 1) v += __shfl_xor(v, o, 64);
        __syncthreads(); if ((j & 63) == 0) s4[j >> 6] = v; __syncthreads();
        float sum12 = s4[0] + s4[1] + s4[2] + s4[3];
        v = s21;
#pragma unroll
        for (int o = 32; o >= 1; o >>= 1) v = fmaxf(v, __shfl_xor(v, o, 64));
        __syncthreads(); if ((j & 63) == 0) s4[j >> 6] = v; __syncthreads();
        float m21 = fmaxf(fmaxf(s4[0], s4[1]), fmaxf(s4[2], s4[3]));
        float e21 = expf(s21 - m21);
        v = e21;
#pragma unroll
        for (int o = 32; o >= 1; o >>= 1) v += __shfl_xor(v, o, 64);
        __syncthreads(); if ((j & 63) == 0) s4[j >> 6] = v; __syncthreads();
        float sum21 = s4[0] + s4[1] + s4[2] + s4[3];

        size_t b0 = (size_t)b * 512 + j, b1 = b0 + 256;
        float x1 = (float)E[b0] * (e12 / sum12);
        float x2 = (float)E[b1] * (e21 / sum21);
        x[b0] = (__bf16)x1;
        x[b1] = (__bf16)x2;
        cro_out[b0] = TAU_F * crohis[b0] + (1.f - TAU_F) * x1;
        cro_out[b1] = TAU_F * crohis[b1] + (1.f - TAU_F) * x2;
    } else {
        int i = ((b - 4096) * 256 + j) * 4;
        f32x4 p = *(const f32x4*)(P5 + i);
        f32x4 ht = *(const f32x4*)(h_tm1 + i);
        int c = i & 511;
        f32x4 o; __bf16 ob[4];
#pragma unroll
        for (int q = 0; q < 4; ++q) {
            float hv = ht[q] + tanhf(p[q] + cw_b[c + q]);
            o[q] = hv; ob[q] = (__bf16)hv;
        }
        *(f32x4*)(hprev + i) = o;
        *(bf16x4*)&hprev_bf[i] = *(bf16x4*)ob;
    }
}

// ---------------- gates: rh = sigmoid(mx_r + bias_r + mi_r) * hprev ----------
__global__ __launch_bounds__(256) void gates_k(
    const float* __restrict__ mx, const float* __restrict__ mi2,
    const float* __restrict__ hprev, const float* __restrict__ bias,
    __bf16* __restrict__ rh)
{
    int i = (blockIdx.x * 256 + threadIdx.x) * 4;
    int row = i >> 9, c = i & 511;
    f32x4 a  = *(const f32x4*)(mx + (size_t)row * 1536 + 512 + c);
    f32x4 m  = *(const f32x4*)(mi2 + (size_t)row * 1024 + 512 + c);
    f32x4 hp = *(const f32x4*)(hprev + i);
    f32x4 bb = *(const f32x4*)(bias + 512 + c);
    __bf16 o[4];
#pragma unroll
    for (int q = 0; q < 4; ++q) {
        float r = 1.f / (1.f + expf(-(a[q] + bb[q] + m[q])));
        o[q] = (__bf16)(r * hp[q]);
    }
    *(bf16x4*)&rh[i] = *(bf16x4*)o;
}

// ---------------- launch -----------------------------------------------------
extern "C" void kernel_launch(void* const* d_in, const int* in_sizes, int n_in,
                              void* d_out, int out_size, void* d_ws, size_t ws_size,
                              hipStream_t stream)
{
    (void)in_sizes; (void)n_in; (void)out_size; (void)ws_size;

    const float* inputs = (const float*)d_in[0];
    const float* h_tm1  = (const float*)d_in[1];
    const float* crohis = (const float*)d_in[2];
    const float* ew1    = (const float*)d_in[3];
    const float* ew2    = (const float*)d_in[4];
    const float* ca12w  = (const float*)d_in[5];
    const float* ca12u  = (const float*)d_in[6];
    const float* ca12v  = (const float*)d_in[7];
    const float* ca21w  = (const float*)d_in[8];
    const float* ca21u  = (const float*)d_in[9];
    const float* ca21v  = (const float*)d_in[10];
    const float* cw_w   = (const float*)d_in[11];
    const float* cw_b   = (const float*)d_in[12];
    const float* cd_w   = (const float*)d_in[13];
    const float* cd_b   = (const float*)d_in[14];
    const float* kern   = (const float*)d_in[15];
    const float* rkern  = (const float*)d_in[16];
    const float* bias   = (const float*)d_in[17];

    char* ws = (char*)d_ws;
    const size_t MB = 1 << 20;
    float*  P12      = (float*)(ws + 0);
    float*  P4       = (float*)(ws + 16 * MB);
    __bf16* T        = (__bf16*)(ws + 16 * MB);
    float*  P5       = (float*)(ws + 32 * MB);
    __bf16* x        = (__bf16*)(ws + 40 * MB);
    __bf16* rh       = (__bf16*)(ws + 40 * MB);
    __bf16* E        = (__bf16*)(ws + 48 * MB);
    __bf16* cro_bf   = (__bf16*)(ws + 52 * MB);
    float*  hprev    = (float*)(ws + 60 * MB);
    __bf16* hprev_bf = (__bf16*)(ws + 68 * MB);
    float*  mx       = (float*)(ws + 0);
    float*  mi2      = (float*)(ws + 24 * MB);
    __bf16* WT       = (__bf16*)(ws + 72 * MB);               // 2MB
    __bf16* WcatT    = (__bf16*)(ws + 74 * MB);               // 1MB
    __bf16* cdT      = (__bf16*)(ws + 75 * MB);               // 0.5MB
    __bf16* cwT      = (__bf16*)(ws + 75 * MB + 512 * 1024);  // 0.5MB
    __bf16* kernT    = (__bf16*)(ws + 76 * MB);               // 1.5MB
    __bf16* rkernT   = (__bf16*)(ws + 77 * MB + 512 * 1024);  // ends 79MB

    float* h_out   = (float*)d_out;
    float* cro_out = (float*)d_out + 2 * 1048576;

    const int BIG = 1 << 30;
    const long long S2 = 1ll << 21;   // 8 MB in fp32 elems

    prep_wT<<<896, 256, 0, stream>>>(ew1, ew2, ca12w, ca12u, ca12v, ca21w,
                                     ca21u, ca21v, cd_w, cw_w, kern, rkern,
                                     WT, WcatT, cdT, cwT, kernT, rkernT);

    // Phase A (AFP32 hybrid): G12 split-2 (fp32 inputs) + G4        [nwg=768]
    SubGemm gA1 = { inputs, 4000, 2000, WT,  2048, P12, 512, S2, 1024, 4, 2, 2000, 0 };
    SubGemm gA2 = { crohis,  512,  512, cdT,  512, P4,  512, 0,   512, 4, BIG, 0, 0 };
    gemm_dual<true><<<dim3(12, 64), 256, 0, stream>>>(gA1, gA2, 8);

    reduce_A<<<4096, 256, 0, stream>>>(P12, P4, cd_b, E, cro_bf);

    // Phase B: G3 (bf16 T out) + G5                                   [nwg=768]
    SubGemm gB1 = { E,      512, 512, WcatT, 512, (float*)T, 1024, 0, 512, 8, BIG, 0, 1 };
    SubGemm gB2 = { cro_bf, 512, 512, cwT,   512, P5,        512,  0, 512, 4, BIG, 0, 0 };
    gemm_dual<false><<<dim3(12, 64), 256, 0, stream>>>(gB1, gB2, 8);

    fuse1<<<6144, 256, 0, stream>>>(T, E, crohis, P5, h_tm1, cw_b,
                                    x, cro_out, hprev, hprev_bf);

    // Phase C: G6 (mx) + G7 (mi2)                                     [nwg=1280]
    SubGemm gC1 = { x,        512, 512, kernT,  512, mx,  1536, 0, 512, 12, BIG, 0, 0 };
    SubGemm gC2 = { hprev_bf, 512, 512, rkernT, 512, mi2, 1024, 0, 512, 8,  BIG, 0, 0 };
    gemm_dual<false><<<dim3(20, 64), 256, 0, stream>>>(gC1, gC2, 12);

    gates_k<<<2048, 256, 0, stream>>>(mx, mi2, hprev, bias, rh);

    // G8 + fused GRU final -> h                                        [nwg=256]
    gemm_g8<<<dim3(4, 64), 256, 0, stream>>>(
        rh, rkernT + (size_t)1024 * 512, mx, mi2, hprev, bias, h_out);
}

// Round 21
// 131.608 us; speedup vs baseline: 1.1808x; 1.1808x over previous
//
#include <hip/hip_runtime.h>
#include <hip/hip_bf16.h>
#include <math.h>

// DscaGRUCell FINAL (= rev 15, best measured 131.87us / 132.07us, 2 runs).
// Pipeline: prep_wT -> [G12+G4] -> reduce_A -> [G3+G5] -> fuse1(attention)
//           -> [G6+G7] -> gates -> [G8 + fused GRU final].
// GEMM core: 64x128 tile, BK=32, 4 waves (2x4 frags 16x16x32 bf16 MFMA),
// 4-buf depth-3 gload_lds pipeline with counted vmcnt(6) (fp32-A: 3-buf
// vmcnt(4)), raw s_barrier, T1 XCD-chunked swizzle. Phase A plateau (~55us)
// is the non-resident 65MB input stream — 9 schedule variants all land
// 54-90us; treated as the structural floor for this decomposition.

#define TAU_F 0.5f

typedef __bf16 bf16x8 __attribute__((ext_vector_type(8)));
typedef __bf16 bf16x4 __attribute__((ext_vector_type(4)));
typedef float f32x4 __attribute__((ext_vector_type(4)));

__device__ __forceinline__ void gload16(const void* g, void* l) {
    __builtin_amdgcn_global_load_lds(
        (const __attribute__((address_space(1))) void*)g,
        (__attribute__((address_space(3))) void*)l, 16, 0, 0);
}

struct SubGemm {
    const void* A;    // M x lda (f32 if AFP32 else bf16)
    int lda;
    int Kvalid;       // AFP32: valid A cols (addr clamp; BT zero-padded beyond)
    const __bf16* BT; // N x Kpad row-major (pre-transposed, zero-padded bf16)
    int ldbt;
    float* C;         // out base (fp32, or bf16 when obf16)
    int ldc;
    long long strideC;
    int Ksub;         // K per split slice (mult of 32)
    int nbx;          // col tiles (N/128)
    int pairSplit;    // ct >= this uses A + pairAOff
    int pairAOff;
    int obf16;        // store bf16 instead of f32
};

template <bool AFP32>
__global__ __launch_bounds__(256) void gemm_dual(SubGemm g1, SubGemm g2, int blocks1)
{
    __shared__ __attribute__((aligned(16))) char lds[49152];

    const int tid = threadIdx.x, w = tid >> 6, l = tid & 63;

    // T1 XCD-chunked swizzle (nwg % 8 == 0 for all launches here)
    const int gx = gridDim.x;
    const int nwg = gx * (int)gridDim.y;
    const int hw = (int)blockIdx.y * gx + (int)blockIdx.x;
    const int lg = (hw & 7) * (nwg >> 3) + (hw >> 3);
    const int bxl_lin = lg % gx;
    const int by = lg / gx;

    const bool second = bxl_lin >= blocks1;
    const SubGemm& g = second ? g2 : g1;
    const int bxl = second ? bxl_lin - blocks1 : bxl_lin;
    const int ct = bxl % g.nbx, spl = bxl / g.nbx;
    const int brow = by * 64, bcol = ct * 128;
    const int k_begin = spl * g.Ksub;
    const int nt = g.Ksub >> 5;
    const int aoff = (ct >= g.pairSplit) ? g.pairAOff : 0;

    const int sbr = w * 32 + (l >> 2);        // B staging rows (2 issues)
    const int seg = (l & 3) * 8;

    const __bf16* Bg0 = g.BT + (size_t)(bcol + sbr) * g.ldbt + seg + k_begin;
    const __bf16* Bg1 = Bg0 + (size_t)16 * g.ldbt;

    f32x4 acc[2][4] = {};
    const int fr = l & 15, fk = (l >> 4) * 8;
    const int wr = (w >> 1) * 32, wc = (w & 1) * 64;
    const int kmax = (nt - 1) * 32;

    if constexpr (AFP32) {
        // LDS: Af32 3 x [64][32] f32 (24KB) | Bs 3 x [128][32] bf16 (24KB)
        auto Af32 = (float (*)[64][32])lds;
        auto Bs   = (__bf16 (*)[128][32])(lds + 24576);

        const float* ArowBase = (const float*)g.A + aoff
                              + (size_t)(brow + w * 16 + (l >> 3)) * g.lda;
        const int colLane = (l & 7) * 4;
        const int kcl4 = g.Kvalid - 4;

#define ISSUE_A32(slot)                                                       \
        {                                                                     \
            const int _s = (slot);                                            \
            const int _k = (_s * 32 < kmax) ? _s * 32 : kmax;                 \
            const int _b = _s % 3;                                            \
            int c0 = k_begin + _k + colLane;                                  \
            c0 = c0 < kcl4 ? c0 : kcl4;                                       \
            gload16(ArowBase + c0,                 &Af32[_b][w * 16][0]);     \
            gload16(ArowBase + 8 * g.lda + c0,     &Af32[_b][w * 16 + 8][0]); \
            gload16(Bg0 + _k, &Bs[_b][w * 32][0]);                            \
            gload16(Bg1 + _k, &Bs[_b][w * 32 + 16][0]);                       \
        }

        ISSUE_A32(0) ISSUE_A32(1)

        for (int t = 0; t < nt; ++t) {
            asm volatile("s_waitcnt vmcnt(4)" ::: "memory");
            asm volatile("s_waitcnt lgkmcnt(0)" ::: "memory");
            __builtin_amdgcn_s_barrier();

            const int bi = t % 3;
            bf16x8 a[2]; bf16x8 b[4];
#pragma unroll
            for (int m = 0; m < 2; ++m) {
                f32x4 lo = *(const f32x4*)&Af32[bi][wr + m * 16 + fr][fk];
                f32x4 hi = *(const f32x4*)&Af32[bi][wr + m * 16 + fr][fk + 4];
#pragma unroll
                for (int z = 0; z < 4; ++z) { a[m][z] = (__bf16)lo[z]; a[m][4 + z] = (__bf16)hi[z]; }
            }
#pragma unroll
            for (int n = 0; n < 4; ++n) b[n] = *(const bf16x8*)&Bs[bi][wc + n * 16 + fr][fk];

            ISSUE_A32(t + 2)

#pragma unroll
            for (int m = 0; m < 2; ++m)
#pragma unroll
                for (int n = 0; n < 4; ++n)
                    acc[m][n] = __builtin_amdgcn_mfma_f32_16x16x32_bf16(a[m], b[n], acc[m][n], 0, 0, 0);
        }
#undef ISSUE_A32
    } else {
        // LDS: As 4 x [64][32] bf16 (16KB) | Bs 4 x [128][32] bf16 (32KB)
        auto As = (__bf16 (*)[64][32])lds;
        auto Bs = (__bf16 (*)[128][32])(lds + 16384);

        const int sar = w * 16 + (l >> 2);
        const __bf16* Ar = (const __bf16*)g.A + aoff
                         + (size_t)(brow + sar) * g.lda + seg + k_begin;

#define ISSUE_AB(slot)                                                        \
        {                                                                     \
            const int _s = (slot);                                            \
            const int _k = (_s * 32 < kmax) ? _s * 32 : kmax;                 \
            const int _b = _s & 3;                                            \
            gload16(Ar + _k,  &As[_b][w * 16][0]);                            \
            gload16(Bg0 + _k, &Bs[_b][w * 32][0]);                            \
            gload16(Bg1 + _k, &Bs[_b][w * 32 + 16][0]);                       \
        }

        ISSUE_AB(0) ISSUE_AB(1) ISSUE_AB(2)

        for (int t = 0; t < nt; ++t) {
            asm volatile("s_waitcnt vmcnt(6)" ::: "memory");
            asm volatile("s_waitcnt lgkmcnt(0)" ::: "memory");
            __builtin_amdgcn_s_barrier();

            const int bi = t & 3;
            bf16x8 a[2], b[4];
#pragma unroll
            for (int m = 0; m < 2; ++m) a[m] = *(const bf16x8*)&As[bi][wr + m * 16 + fr][fk];
#pragma unroll
            for (int n = 0; n < 4; ++n) b[n] = *(const bf16x8*)&Bs[bi][wc + n * 16 + fr][fk];

            ISSUE_AB(t + 3)

#pragma unroll
            for (int m = 0; m < 2; ++m)
#pragma unroll
                for (int n = 0; n < 4; ++n)
                    acc[m][n] = __builtin_amdgcn_mfma_f32_16x16x32_bf16(a[m], b[n], acc[m][n], 0, 0, 0);
        }
#undef ISSUE_AB
    }

    // epilogue. C/D: col=lane&15, row=(lane>>4)*4+reg
    const int fq = (l >> 4) * 4;
    if (g.obf16) {
        __bf16* Cb = (__bf16*)g.C + (size_t)spl * g.strideC;
#pragma unroll
        for (int m = 0; m < 2; ++m)
#pragma unroll
            for (int n = 0; n < 4; ++n)
#pragma unroll
                for (int r = 0; r < 4; ++r) {
                    int row = brow + wr + m * 16 + fq + r;
                    int col = bcol + wc + n * 16 + fr;
                    Cb[(size_t)row * g.ldc + col] = (__bf16)acc[m][n][r];
                }
    } else {
        float* C = g.C + (size_t)spl * g.strideC;
#pragma unroll
        for (int m = 0; m < 2; ++m)
#pragma unroll
            for (int n = 0; n < 4; ++n)
#pragma unroll
                for (int r = 0; r < 4; ++r) {
                    int row = brow + wr + m * 16 + fq + r;
                    int col = bcol + wc + n * 16 + fr;
                    C[(size_t)row * g.ldc + col] = acc[m][n][r];
                }
    }
}

// ---------------- G8 + fused GRU final: h = z*hprev + (1-z)*tanh(xh+acc) ----
__global__ __launch_bounds__(256) void gemm_g8(
    const __bf16* __restrict__ A, const __bf16* __restrict__ BT,
    const float* __restrict__ mx, const float* __restrict__ mi2,
    const float* __restrict__ hprev, const float* __restrict__ bias,
    float* __restrict__ h)
{
    __shared__ __attribute__((aligned(16))) char lds[49152];

    const int tid = threadIdx.x, w = tid >> 6, l = tid & 63;

    const int gx = gridDim.x;
    const int nwg = gx * (int)gridDim.y;
    const int hw = (int)blockIdx.y * gx + (int)blockIdx.x;
    const int lg = (hw & 7) * (nwg >> 3) + (hw >> 3);
    const int ct = lg % gx;
    const int by = lg / gx;

    const int brow = by * 64, bcol = ct * 128;
    const int nt = 16;                         // K = 512

    const int sbr = w * 32 + (l >> 2);
    const int seg = (l & 3) * 8;

    const __bf16* Bg0 = BT + (size_t)(bcol + sbr) * 512 + seg;
    const __bf16* Bg1 = Bg0 + (size_t)16 * 512;

    f32x4 acc[2][4] = {};
    const int fr = l & 15, fk = (l >> 4) * 8;
    const int wr = (w >> 1) * 32, wc = (w & 1) * 64;
    const int kmax = (nt - 1) * 32;

    auto As = (__bf16 (*)[64][32])lds;
    auto Bs = (__bf16 (*)[128][32])(lds + 16384);

    const int sar = w * 16 + (l >> 2);
    const __bf16* Ar = A + (size_t)(brow + sar) * 512 + seg;

#define ISSUE_G8(slot)                                                        \
    {                                                                         \
        const int _s = (slot);                                                \
        const int _k = (_s * 32 < kmax) ? _s * 32 : kmax;                     \
        const int _b = _s & 3;                                                \
        gload16(Ar + _k,  &As[_b][w * 16][0]);                                \
        gload16(Bg0 + _k, &Bs[_b][w * 32][0]);                                \
        gload16(Bg1 + _k, &Bs[_b][w * 32 + 16][0]);                           \
    }

    ISSUE_G8(0) ISSUE_G8(1) ISSUE_G8(2)

    for (int t = 0; t < nt; ++t) {
        asm volatile("s_waitcnt vmcnt(6)" ::: "memory");
        asm volatile("s_waitcnt lgkmcnt(0)" ::: "memory");
        __builtin_amdgcn_s_barrier();

        const int bi = t & 3;
        bf16x8 a[2], b[4];
#pragma unroll
        for (int m = 0; m < 2; ++m) a[m] = *(const bf16x8*)&As[bi][wr + m * 16 + fr][fk];
#pragma unroll
        for (int n = 0; n < 4; ++n) b[n] = *(const bf16x8*)&Bs[bi][wc + n * 16 + fr][fk];

        ISSUE_G8(t + 3)

#pragma unroll
        for (int m = 0; m < 2; ++m)
#pragma unroll
            for (int n = 0; n < 4; ++n)
                acc[m][n] = __builtin_amdgcn_mfma_f32_16x16x32_bf16(a[m], b[n], acc[m][n], 0, 0, 0);
    }
#undef ISSUE_G8

    // fused GRU final epilogue
    const int fq = (l >> 4) * 4;
#pragma unroll
    for (int m = 0; m < 2; ++m)
#pragma unroll
        for (int n = 0; n < 4; ++n)
#pragma unroll
            for (int r = 0; r < 4; ++r) {
                int row = brow + wr + m * 16 + fq + r;
                int col = bcol + wc + n * 16 + fr;
                float xz = mx[(size_t)row * 1536 + col]        + bias[col];
                float xh = mx[(size_t)row * 1536 + 1024 + col] + bias[1024 + col];
                float mz = mi2[(size_t)row * 1024 + col];
                float hp = hprev[(size_t)row * 512 + col];
                float z  = 1.f / (1.f + expf(-(xz + mz)));
                float hh = tanhf(xh + acc[m][n][r]);
                h[(size_t)row * 512 + col] = z * hp + (1.f - z) * hh;
            }
}

// ---------------- prep: LDS-tiled weight transposes --------------------------
__global__ __launch_bounds__(256) void prep_wT(
    const float* __restrict__ ew1, const float* __restrict__ ew2,
    const float* __restrict__ w12, const float* __restrict__ u12,
    const float* __restrict__ v12, const float* __restrict__ w21,
    const float* __restrict__ u21, const float* __restrict__ v21,
    const float* __restrict__ cd_w, const float* __restrict__ cw_w,
    const float* __restrict__ kern, const float* __restrict__ rkern,
    __bf16* __restrict__ WT, __bf16* __restrict__ WcatT,
    __bf16* __restrict__ cdT, __bf16* __restrict__ cwT,
    __bf16* __restrict__ kernT, __bf16* __restrict__ rkernT)
{
    __shared__ float tile[64][65];
    const int b = blockIdx.x, tid = threadIdx.x;
    const int tr = tid >> 6, tc = tid & 63;

    const float* src = nullptr;
    int ldsrc = 0, srow0 = 0, scol0 = 0, kvalid = 1 << 30;
    __bf16* dst; int ldd, n0, k0;
    bool zero = false;

    if (b < 256) {                         // WT: out 512 x 2048
        int q = b; n0 = (q >> 5) * 64; k0 = (q & 31) * 64;
        dst = WT; ldd = 2048; kvalid = 2000; ldsrc = 256; srow0 = k0;
        if (n0 < 256) { src = ew1; scol0 = n0; } else { src = ew2; scol0 = n0 - 256; }
    } else if (b < 384) {                  // WcatT: out 1024 x 512
        int q = b - 256; n0 = (q >> 3) * 64; k0 = (q & 7) * 64;
        dst = WcatT; ldd = 512; ldsrc = 256; srow0 = k0 & 255; scol0 = n0 & 255;
        int qn = n0 >> 8; bool khi = k0 >= 256;
        if (qn == 0)      src = khi ? u12 : w12;
        else if (qn == 1) src = khi ? w21 : u21;
        else if (qn == 2) { if (khi) src = v12; else zero = true; }
        else              { if (khi) zero = true; else src = v21; }
    } else if (b < 448) {                  // cdT
        int q = b - 384; n0 = (q >> 3) * 64; k0 = (q & 7) * 64;
        src = cd_w; ldsrc = 512; srow0 = k0; scol0 = n0; dst = cdT; ldd = 512;
    } else if (b < 512) {                  // cwT
        int q = b - 448; n0 = (q >> 3) * 64; k0 = (q & 7) * 64;
        src = cw_w; ldsrc = 512; srow0 = k0; scol0 = n0; dst = cwT; ldd = 512;
    } else if (b < 704) {                  // kernT
        int q = b - 512; n0 = (q >> 3) * 64; k0 = (q & 7) * 64;
        src = kern; ldsrc = 1536; srow0 = k0; scol0 = n0; dst = kernT; ldd = 512;
    } else {                               // rkernT
        int q = b - 704; n0 = (q >> 3) * 64; k0 = (q & 7) * 64;
        src = rkern; ldsrc = 1536; srow0 = k0; scol0 = n0; dst = rkernT; ldd = 512;
    }

#pragma unroll
    for (int p = 0; p < 16; ++p) {
        int kr = p * 4 + tr;
        float v = 0.f;
        if (!zero && (srow0 + kr) < kvalid)
            v = src[(size_t)(srow0 + kr) * ldsrc + scol0 + tc];
        tile[kr][tc] = v;
    }
    __syncthreads();
#pragma unroll
    for (int p = 0; p < 16; ++p) {
        int nr = p * 4 + tr;
        dst[(size_t)(n0 + nr) * ldd + k0 + tc] = (__bf16)tile[tc][nr];
    }
}

// ---------------- R-A: E = bf16(sum2 P12), cro = bf16(tanh(P4 + cd_b)) ------
__global__ __launch_bounds__(256) void reduce_A(
    const float* __restrict__ P12, const float* __restrict__ P4,
    const float* __restrict__ cd_b,
    __bf16* __restrict__ E, __bf16* __restrict__ cro)
{
    const int S = 1 << 21;
    int b = blockIdx.x;
    int i = (((b & 2047) * 256) + threadIdx.x) * 4;
    if (b < 2048) {
        f32x4 p0 = *(const f32x4*)(P12 + i);
        f32x4 p1 = *(const f32x4*)(P12 + S + i);
        __bf16 o[4];
#pragma unroll
        for (int j = 0; j < 4; ++j) o[j] = (__bf16)(p0[j] + p1[j]);
        *(bf16x4*)&E[i] = *(bf16x4*)o;
    } else {
        f32x4 p0 = *(const f32x4*)(P4 + i);
        int c = i & 511;
        __bf16 o[4];
#pragma unroll
        for (int j = 0; j < 4; ++j) o[j] = (__bf16)tanhf(p0[j] + cd_b[c + j]);
        *(bf16x4*)&cro[i] = *(bf16x4*)o;
    }
}

// ---------------- fuse1: attention + x + crohis_new, and hprev ---------------
__global__ __launch_bounds__(256) void fuse1(
    const __bf16* __restrict__ T, const __bf16* __restrict__ E,
    const float* __restrict__ crohis,
    const float* __restrict__ P5,
    const float* __restrict__ h_tm1, const float* __restrict__ cw_b,
    __bf16* __restrict__ x, float* __restrict__ cro_out,
    float* __restrict__ hprev, __bf16* __restrict__ hprev_bf)
{
    __shared__ float s4[4];
    int b = blockIdx.x;
    int j = threadIdx.x;
    if (b < 4096) {
        const __bf16* t = T + (size_t)b * 1024;
        float s12 = tanhf((float)t[j])       * (float)t[512 + j];
        float s21 = tanhf((float)t[256 + j]) * (float)t[768 + j];
        float v = s12;
#pragma unroll
        for (int o = 32; o >= 1; o >>= 1) v = fmaxf(v, __shfl_xor(v, o, 64));
        __syncthreads(); if ((j & 63) == 0) s4[j >> 6] = v; __syncthreads();
        float m12 = fmaxf(fmaxf(s4[0], s4[1]), fmaxf(s4[2], s4[3]));
        float e12 = expf(s12 - m12);
        v = e12;
#pragma unroll
        for (int o = 32; o >= 1; o >>= 1) v += __shfl_xor(v, o, 64);
        __syncthreads(); if ((j & 63) == 0) s4[j >> 6] = v; __syncthreads();
        float sum12 = s4[0] + s4[1] + s4[2] + s4[3];
        v = s21;
#pragma unroll
        for (int o = 32; o >= 1; o >>= 1) v = fmaxf(v, __shfl_xor(v, o, 64));
        __syncthreads(); if ((j & 63) == 0) s4[j >> 6] = v; __syncthreads();
        float m21 = fmaxf(fmaxf(s4[0], s4[1]), fmaxf(s4[2], s4[3]));
        float e21 = expf(s21 - m21);
        v = e21;
#pragma unroll
        for (int o = 32; o >= 1; o >>= 1) v += __shfl_xor(v, o, 64);
        __syncthreads(); if ((j & 63) == 0) s4[j >> 6] = v; __syncthreads();
        float sum21 = s4[0] + s4[1] + s4[2] + s4[3];

        size_t b0 = (size_t)b * 512 + j, b1 = b0 + 256;
        float x1 = (float)E[b0] * (e12 / sum12);
        float x2 = (float)E[b1] * (e21 / sum21);
        x[b0] = (__bf16)x1;
        x[b1] = (__bf16)x2;
        cro_out[b0] = TAU_F * crohis[b0] + (1.f - TAU_F) * x1;
        cro_out[b1] = TAU_F * crohis[b1] + (1.f - TAU_F) * x2;
    } else {
        int i = ((b - 4096) * 256 + j) * 4;
        f32x4 p = *(const f32x4*)(P5 + i);
        f32x4 ht = *(const f32x4*)(h_tm1 + i);
        int c = i & 511;
        f32x4 o; __bf16 ob[4];
#pragma unroll
        for (int q = 0; q < 4; ++q) {
            float hv = ht[q] + tanhf(p[q] + cw_b[c + q]);
            o[q] = hv; ob[q] = (__bf16)hv;
        }
        *(f32x4*)(hprev + i) = o;
        *(bf16x4*)&hprev_bf[i] = *(bf16x4*)ob;
    }
}

// ---------------- gates: rh = sigmoid(mx_r + bias_r + mi_r) * hprev ----------
__global__ __launch_bounds__(256) void gates_k(
    const float* __restrict__ mx, const float* __restrict__ mi2,
    const float* __restrict__ hprev, const float* __restrict__ bias,
    __bf16* __restrict__ rh)
{
    int i = (blockIdx.x * 256 + threadIdx.x) * 4;
    int row = i >> 9, c = i & 511;
    f32x4 a  = *(const f32x4*)(mx + (size_t)row * 1536 + 512 + c);
    f32x4 m  = *(const f32x4*)(mi2 + (size_t)row * 1024 + 512 + c);
    f32x4 hp = *(const f32x4*)(hprev + i);
    f32x4 bb = *(const f32x4*)(bias + 512 + c);
    __bf16 o[4];
#pragma unroll
    for (int q = 0; q < 4; ++q) {
        float r = 1.f / (1.f + expf(-(a[q] + bb[q] + m[q])));
        o[q] = (__bf16)(r * hp[q]);
    }
    *(bf16x4*)&rh[i] = *(bf16x4*)o;
}

// ---------------- launch -----------------------------------------------------
extern "C" void kernel_launch(void* const* d_in, const int* in_sizes, int n_in,
                              void* d_out, int out_size, void* d_ws, size_t ws_size,
                              hipStream_t stream)
{
    (void)in_sizes; (void)n_in; (void)out_size; (void)ws_size;

    const float* inputs = (const float*)d_in[0];
    const float* h_tm1  = (const float*)d_in[1];
    const float* crohis = (const float*)d_in[2];
    const float* ew1    = (const float*)d_in[3];
    const float* ew2    = (const float*)d_in[4];
    const float* ca12w  = (const float*)d_in[5];
    const float* ca12u  = (const float*)d_in[6];
    const float* ca12v  = (const float*)d_in[7];
    const float* ca21w  = (const float*)d_in[8];
    const float* ca21u  = (const float*)d_in[9];
    const float* ca21v  = (const float*)d_in[10];
    const float* cw_w   = (const float*)d_in[11];
    const float* cw_b   = (const float*)d_in[12];
    const float* cd_w   = (const float*)d_in[13];
    const float* cd_b   = (const float*)d_in[14];
    const float* kern   = (const float*)d_in[15];
    const float* rkern  = (const float*)d_in[16];
    const float* bias   = (const float*)d_in[17];

    char* ws = (char*)d_ws;
    const size_t MB = 1 << 20;
    float*  P12      = (float*)(ws + 0);
    float*  P4       = (float*)(ws + 16 * MB);
    __bf16* T        = (__bf16*)(ws + 16 * MB);
    float*  P5       = (float*)(ws + 32 * MB);
    __bf16* x        = (__bf16*)(ws + 40 * MB);
    __bf16* rh       = (__bf16*)(ws + 40 * MB);
    __bf16* E        = (__bf16*)(ws + 48 * MB);
    __bf16* cro_bf   = (__bf16*)(ws + 52 * MB);
    float*  hprev    = (float*)(ws + 60 * MB);
    __bf16* hprev_bf = (__bf16*)(ws + 68 * MB);
    float*  mx       = (float*)(ws + 0);
    float*  mi2      = (float*)(ws + 24 * MB);
    __bf16* WT       = (__bf16*)(ws + 72 * MB);               // 2MB
    __bf16* WcatT    = (__bf16*)(ws + 74 * MB);               // 1MB
    __bf16* cdT      = (__bf16*)(ws + 75 * MB);               // 0.5MB
    __bf16* cwT      = (__bf16*)(ws + 75 * MB + 512 * 1024);  // 0.5MB
    __bf16* kernT    = (__bf16*)(ws + 76 * MB);               // 1.5MB
    __bf16* rkernT   = (__bf16*)(ws + 77 * MB + 512 * 1024);  // ends 79MB

    float* h_out   = (float*)d_out;
    float* cro_out = (float*)d_out + 2 * 1048576;

    const int BIG = 1 << 30;
    const long long S2 = 1ll << 21;   // 8 MB in fp32 elems

    prep_wT<<<896, 256, 0, stream>>>(ew1, ew2, ca12w, ca12u, ca12v, ca21w,
                                     ca21u, ca21v, cd_w, cw_w, kern, rkern,
                                     WT, WcatT, cdT, cwT, kernT, rkernT);

    // Phase A (AFP32): G12 split-2 (fp32 inputs) + G4 (fp32 crohis)  [nwg=768]
    SubGemm gA1 = { inputs, 4000, 2000, WT,  2048, P12, 512, S2, 1024, 4, 2, 2000, 0 };
    SubGemm gA2 = { crohis,  512,  512, cdT,  512, P4,  512, 0,   512, 4, BIG, 0, 0 };
    gemm_dual<true><<<dim3(12, 64), 256, 0, stream>>>(gA1, gA2, 8);

    reduce_A<<<4096, 256, 0, stream>>>(P12, P4, cd_b, E, cro_bf);

    // Phase B: G3 (bf16 T out) + G5                                   [nwg=768]
    SubGemm gB1 = { E,      512, 512, WcatT, 512, (float*)T, 1024, 0, 512, 8, BIG, 0, 1 };
    SubGemm gB2 = { cro_bf, 512, 512, cwT,   512, P5,        512,  0, 512, 4, BIG, 0, 0 };
    gemm_dual<false><<<dim3(12, 64), 256, 0, stream>>>(gB1, gB2, 8);

    fuse1<<<6144, 256, 0, stream>>>(T, E, crohis, P5, h_tm1, cw_b,
                                    x, cro_out, hprev, hprev_bf);

    // Phase C: G6 (mx) + G7 (mi2)                                     [nwg=1280]
    SubGemm gC1 = { x,        512, 512, kernT,  512, mx,  1536, 0, 512, 12, BIG, 0, 0 };
    SubGemm gC2 = { hprev_bf, 512, 512, rkernT, 512, mi2, 1024, 0, 512, 8,  BIG, 0, 0 };
    gemm_dual<false><<<dim3(20, 64), 256, 0, stream>>>(gC1, gC2, 12);

    gates_k<<<2048, 256, 0, stream>>>(mx, mi2, hprev, bias, rh);

    // G8 + fused GRU final -> h                                        [nwg=256]
    gemm_g8<<<dim3(4, 64), 256, 0, stream>>>(
        rh, rkernT + (size_t)1024 * 512, mx, mi2, hprev, bias, h_out);
}